// Round 1
// baseline (372.092 us; speedup 1.0000x reference)
//
#include <hip/hip_runtime.h>
#include <math.h>

#define D 128
#define BR 64
#define BK 32

// ---------------- Kernel 1: Y = X @ W  (X: [N,128], W: [128,128]) ----------------
// block 256 threads; tile 64 rows x 128 cols; micro-tile 4 rows x 8 cols per thread.
__global__ __launch_bounds__(256) void gemm_xw_kernel(
    const float* __restrict__ X, const float* __restrict__ W,
    float* __restrict__ Y, int N)
{
  // sX transposed: sX[k][r]; stride 68 floats = 272 B (16B-aligned for b128 reads)
  __shared__ __align__(16) float sX[BK][BR + 4];
  __shared__ __align__(16) float sW[BK][D];

  const int tid  = threadIdx.x;
  const int row0 = blockIdx.x * BR;
  const int tr   = tid >> 4;   // 0..15 -> rows tr*4 .. tr*4+3
  const int tc   = tid & 15;   // 0..15 -> cols tc*8 .. tc*8+7

  float acc[4][8];
  #pragma unroll
  for (int r = 0; r < 4; r++)
    #pragma unroll
    for (int c = 0; c < 8; c++) acc[r][c] = 0.0f;

  for (int k0 = 0; k0 < D; k0 += BK) {
    // stage W tile: BK*128 = 4096 floats = 1024 float4; 4 per thread, coalesced
    {
      const float4* Wg  = (const float4*)(W + (size_t)k0 * D);
      float4*       sWv = (float4*)(&sW[0][0]);
      #pragma unroll
      for (int i = 0; i < 4; i++)
        sWv[tid + i * 256] = Wg[tid + i * 256];
    }
    // stage X tile transposed: 64 rows x 32 k = 512 float4; 2 per thread
    {
      int idx = tid;
      #pragma unroll
      for (int i = 0; i < 2; i++, idx += 256) {
        int r  = idx >> 3;   // 0..63  (row within tile)
        int kq = idx & 7;    // float4 index within 32-float k chunk
        int grow = row0 + r;
        float4 v = make_float4(0.f, 0.f, 0.f, 0.f);
        if (grow < N)
          v = *(const float4*)(X + (size_t)grow * D + k0 + kq * 4);
        sX[kq * 4 + 0][r] = v.x;
        sX[kq * 4 + 1][r] = v.y;
        sX[kq * 4 + 2][r] = v.z;
        sX[kq * 4 + 3][r] = v.w;
      }
    }
    __syncthreads();

    #pragma unroll
    for (int k = 0; k < BK; k++) {
      float a[4], w[8];
      *(float4*)&a[0] = *(const float4*)&sX[k][tr * 4];
      *(float4*)&w[0] = *(const float4*)&sW[k][tc * 8];
      *(float4*)&w[4] = *(const float4*)&sW[k][tc * 8 + 4];
      #pragma unroll
      for (int r = 0; r < 4; r++)
        #pragma unroll
        for (int c = 0; c < 8; c++)
          acc[r][c] = fmaf(a[r], w[c], acc[r][c]);
    }
    __syncthreads();
  }

  #pragma unroll
  for (int r = 0; r < 4; r++) {
    int grow = row0 + tr * 4 + r;
    if (grow < N) {
      float4* dst = (float4*)(Y + (size_t)grow * D + tc * 8);
      dst[0] = *(float4*)&acc[r][0];
      dst[1] = *(float4*)&acc[r][4];
    }
  }
}

// ---------------- Kernel 2: out[e] = sigmoid(Y[src_e] . Xin[dst_e]) ----------------
// 16 lanes per edge; each lane: 2x float4 from each row; shfl_xor reduce over 16 lanes.
__global__ __launch_bounds__(256) void edge_dot_kernel(
    const float* __restrict__ Y, const float* __restrict__ Xin,
    const int* __restrict__ idx, float* __restrict__ out, int E)
{
  long long gid = (long long)blockIdx.x * 256 + threadIdx.x;
  int e = (int)(gid >> 4);
  if (e >= E) return;
  int l = (int)(gid & 15);

  int src = idx[e];        // edge_index[0][e]
  int dst = idx[E + e];    // edge_index[1][e]

  const float4* yr = (const float4*)(Y   + (size_t)src * D);
  const float4* br = (const float4*)(Xin + (size_t)dst * D);

  float4 a0 = yr[l];
  float4 b0 = br[l];
  float4 a1 = yr[l + 16];
  float4 b1 = br[l + 16];

  float s = a0.x * b0.x + a0.y * b0.y + a0.z * b0.z + a0.w * b0.w
          + a1.x * b1.x + a1.y * b1.y + a1.z * b1.z + a1.w * b1.w;

  s += __shfl_xor(s, 8);
  s += __shfl_xor(s, 4);
  s += __shfl_xor(s, 2);
  s += __shfl_xor(s, 1);

  if (l == 0)
    out[e] = 1.0f / (1.0f + __expf(-s));
}

// ---------------- Fallback: direct bilinear per edge (1 wave/edge), only if ws too small ---
__global__ __launch_bounds__(256) void edge_bilinear_direct_kernel(
    const float* __restrict__ Xout, const float* __restrict__ Xin,
    const float* __restrict__ W, const int* __restrict__ idx,
    float* __restrict__ out, int E)
{
  long long gid = (long long)blockIdx.x * 256 + threadIdx.x;
  int e = (int)(gid >> 6);           // one 64-lane wave per edge
  if (e >= E) return;
  int l = (int)(gid & 63);

  int src = idx[e];
  int dst = idx[E + e];
  const float* a = Xout + (size_t)src * D;
  const float* b = Xin  + (size_t)dst * D;

  float s = 0.f;
  #pragma unroll
  for (int kk = 0; kk < 2; kk++) {
    int k = l + kk * 64;
    float ak = a[k];
    float t = 0.f;
    const float* wr = W + (size_t)k * D;
    #pragma unroll 8
    for (int j = 0; j < D; j++) t = fmaf(wr[j], b[j], t);
    s = fmaf(ak, t, s);
  }
  #pragma unroll
  for (int off = 32; off >= 1; off >>= 1) s += __shfl_xor(s, off);
  if (l == 0) out[e] = 1.0f / (1.0f + __expf(-s));
}

extern "C" void kernel_launch(void* const* d_in, const int* in_sizes, int n_in,
                              void* d_out, int out_size, void* d_ws, size_t ws_size,
                              hipStream_t stream) {
  const float* x_in  = (const float*)d_in[0];   // [N, 128]
  const float* x_out = (const float*)d_in[1];   // [N, 128]
  const int*   eidx  = (const int*)d_in[2];     // [2, E]
  const float* W     = (const float*)d_in[3];   // [1, 128, 128] -> [128,128]
  float* out = (float*)d_out;

  const int N = in_sizes[0] / D;
  const int E = in_sizes[2] / 2;

  size_t y_bytes = (size_t)N * D * sizeof(float);

  if (ws_size >= y_bytes) {
    float* Y = (float*)d_ws;
    dim3 g1((N + BR - 1) / BR);
    gemm_xw_kernel<<<g1, 256, 0, stream>>>(x_out, W, Y, N);

    long long total = (long long)E * 16;
    dim3 g2((unsigned)((total + 255) / 256));
    edge_dot_kernel<<<g2, 256, 0, stream>>>(Y, x_in, eidx, out, E);
  } else {
    long long total = (long long)E * 64;
    dim3 g((unsigned)((total + 255) / 256));
    edge_bilinear_direct_kernel<<<g, 256, 0, stream>>>(x_out, x_in, W, eidx, out, E);
  }
}

// Round 2
// 284.542 us; speedup vs baseline: 1.3077x; 1.3077x over previous
//
#include <hip/hip_runtime.h>
#include <hip/hip_fp16.h>
#include <math.h>

#define D 128
#define TM 128   // GEMM tile rows
#define BKk 32   // GEMM k-chunk
#define XPAD 4   // sX leading-dim pad (keeps 16B alignment, 2-way-max write conflicts)

typedef _Float16 h2_t __attribute__((ext_vector_type(2)));

__device__ __forceinline__ float dot2acc(unsigned ua, unsigned ub, float c) {
#if __has_builtin(__builtin_amdgcn_fdot2)
  return __builtin_amdgcn_fdot2(__builtin_bit_cast(h2_t, ua),
                                __builtin_bit_cast(h2_t, ub), c, false);
#else
  __half2 a = __builtin_bit_cast(__half2, ua);
  __half2 b = __builtin_bit_cast(__half2, ub);
  float2 fa = __half22float2(a), fb = __half22float2(b);
  return fmaf(fa.x, fb.x, fmaf(fa.y, fb.y, c));
#endif
}

// ---------------- Kernel 0: x_in (fp32) -> fp16 ----------------
__global__ __launch_bounds__(256) void convert_f16_kernel(
    const float* __restrict__ x, __half* __restrict__ xh, int n4)
{
  int i = blockIdx.x * 256 + threadIdx.x;
  if (i >= n4) return;
  float4 v = ((const float4*)x)[i];
  __half2 h0, h1;
  h0.x = __float2half_rn(v.x); h0.y = __float2half_rn(v.y);
  h1.x = __float2half_rn(v.z); h1.y = __float2half_rn(v.w);
  uint2 u;
  u.x = __builtin_bit_cast(unsigned, h0);
  u.y = __builtin_bit_cast(unsigned, h1);
  ((uint2*)xh)[i] = u;
}

// ---------------- Kernel 1: Y = X @ W (fp32 math), Y stored fp16 ----------------
// 256 threads, 128x128 tile, 8x8 micro-tile. Columns per thread: {tc*4..+3, 64+tc*4..+3}
// so the sW read is 2 b128 with only 2-way bank aliasing (free).
__global__ __launch_bounds__(256) void gemm_xw_f16_kernel(
    const float* __restrict__ X, const float* __restrict__ W,
    __half* __restrict__ Y, int N)
{
  __shared__ __align__(16) float sX[BKk][TM + XPAD];  // transposed: sX[k][r]
  __shared__ __align__(16) float sW[BKk][D];

  const int tid  = threadIdx.x;
  const int row0 = blockIdx.x * TM;
  const int tr   = tid >> 4;   // 0..15 -> rows tr*8 .. tr*8+7
  const int tc   = tid & 15;   // cols tc*4..+3 and 64+tc*4..+3

  float acc[8][8];
  #pragma unroll
  for (int r = 0; r < 8; r++)
    #pragma unroll
    for (int c = 0; c < 8; c++) acc[r][c] = 0.0f;

  for (int k0 = 0; k0 < D; k0 += BKk) {
    // stage W tile: 32x128 = 1024 float4, 4 per thread, coalesced
    {
      const float4* Wg  = (const float4*)(W + (size_t)k0 * D);
      float4*       sWv = (float4*)(&sW[0][0]);
      #pragma unroll
      for (int i = 0; i < 4; i++)
        sWv[tid + i * 256] = Wg[tid + i * 256];
    }
    // stage X tile transposed: 128 rows x 32 k = 1024 float4, 4 per thread.
    // idx: kq = idx&7 (8 float4 per row), r = idx>>3 -> coalesced 128B per 8 lanes.
    {
      #pragma unroll
      for (int i = 0; i < 4; i++) {
        int idx = tid + i * 256;
        int kq  = idx & 7;
        int r   = idx >> 3;
        int grow = row0 + r;
        float4 v = make_float4(0.f, 0.f, 0.f, 0.f);
        if (grow < N)
          v = *(const float4*)(X + (size_t)grow * D + k0 + kq * 4);
        sX[kq * 4 + 0][r] = v.x;
        sX[kq * 4 + 1][r] = v.y;
        sX[kq * 4 + 2][r] = v.z;
        sX[kq * 4 + 3][r] = v.w;
      }
    }
    __syncthreads();

    #pragma unroll 8
    for (int k = 0; k < BKk; k++) {
      float a[8], w[8];
      *(float4*)&a[0] = *(const float4*)&sX[k][tr * 8];
      *(float4*)&a[4] = *(const float4*)&sX[k][tr * 8 + 4];
      *(float4*)&w[0] = *(const float4*)&sW[k][tc * 4];
      *(float4*)&w[4] = *(const float4*)&sW[k][64 + tc * 4];
      #pragma unroll
      for (int r = 0; r < 8; r++)
        #pragma unroll
        for (int c = 0; c < 8; c++)
          acc[r][c] = fmaf(a[r], w[c], acc[r][c]);
    }
    __syncthreads();
  }

  #pragma unroll
  for (int r = 0; r < 8; r++) {
    int grow = row0 + tr * 8 + r;
    if (grow < N) {
      __half* yrow = Y + (size_t)grow * D;
      __half2 h0, h1;
      h0.x = __float2half_rn(acc[r][0]); h0.y = __float2half_rn(acc[r][1]);
      h1.x = __float2half_rn(acc[r][2]); h1.y = __float2half_rn(acc[r][3]);
      uint2 u0;
      u0.x = __builtin_bit_cast(unsigned, h0);
      u0.y = __builtin_bit_cast(unsigned, h1);
      *(uint2*)(yrow + tc * 4) = u0;
      h0.x = __float2half_rn(acc[r][4]); h0.y = __float2half_rn(acc[r][5]);
      h1.x = __float2half_rn(acc[r][6]); h1.y = __float2half_rn(acc[r][7]);
      uint2 u1;
      u1.x = __builtin_bit_cast(unsigned, h0);
      u1.y = __builtin_bit_cast(unsigned, h1);
      *(uint2*)(yrow + 64 + tc * 4) = u1;
    }
  }
}

// ---------------- Kernel 2: out[e] = sigmoid(Yh[src_e] . Xh[dst_e]) ----------------
// fp16 rows (256 B). 16 lanes per edge, one uint4 (8 halves) per row per lane.
__global__ __launch_bounds__(256) void edge_dot_f16_kernel(
    const __half* __restrict__ Yh, const __half* __restrict__ Xh,
    const int* __restrict__ idx, float* __restrict__ out, int E)
{
  long long gid = (long long)blockIdx.x * 256 + threadIdx.x;
  int e = (int)(gid >> 4);
  if (e >= E) return;
  int l = (int)(gid & 15);

  int src = idx[e];        // edge_index[0][e]
  int dst = idx[E + e];    // edge_index[1][e]

  uint4 ya = ((const uint4*)(Yh + (size_t)src * D))[l];
  uint4 xb = ((const uint4*)(Xh + (size_t)dst * D))[l];

  float s = 0.0f;
  s = dot2acc(ya.x, xb.x, s);
  s = dot2acc(ya.y, xb.y, s);
  s = dot2acc(ya.z, xb.z, s);
  s = dot2acc(ya.w, xb.w, s);

  s += __shfl_xor(s, 8);
  s += __shfl_xor(s, 4);
  s += __shfl_xor(s, 2);
  s += __shfl_xor(s, 1);

  if (l == 0)
    out[e] = 1.0f / (1.0f + __expf(-s));
}

// ---------------- Fallback: direct bilinear per edge (only if ws too small) ----------
__global__ __launch_bounds__(256) void edge_bilinear_direct_kernel(
    const float* __restrict__ Xout, const float* __restrict__ Xin,
    const float* __restrict__ W, const int* __restrict__ idx,
    float* __restrict__ out, int E)
{
  long long gid = (long long)blockIdx.x * 256 + threadIdx.x;
  int e = (int)(gid >> 6);
  if (e >= E) return;
  int l = (int)(gid & 63);

  int src = idx[e];
  int dst = idx[E + e];
  const float* a = Xout + (size_t)src * D;
  const float* b = Xin  + (size_t)dst * D;

  float s = 0.f;
  #pragma unroll
  for (int kk = 0; kk < 2; kk++) {
    int k = l + kk * 64;
    float ak = a[k];
    float t = 0.f;
    const float* wr = W + (size_t)k * D;
    #pragma unroll 8
    for (int j = 0; j < D; j++) t = fmaf(wr[j], b[j], t);
    s = fmaf(ak, t, s);
  }
  #pragma unroll
  for (int off = 32; off >= 1; off >>= 1) s += __shfl_xor(s, off);
  if (l == 0) out[e] = 1.0f / (1.0f + __expf(-s));
}

extern "C" void kernel_launch(void* const* d_in, const int* in_sizes, int n_in,
                              void* d_out, int out_size, void* d_ws, size_t ws_size,
                              hipStream_t stream) {
  const float* x_in  = (const float*)d_in[0];   // [N, 128]
  const float* x_out = (const float*)d_in[1];   // [N, 128]
  const int*   eidx  = (const int*)d_in[2];     // [2, E] (harness converts to int32)
  const float* W     = (const float*)d_in[3];   // [128,128]
  float* out = (float*)d_out;

  const int N = in_sizes[0] / D;
  const int E = in_sizes[2] / 2;

  size_t half_rows = (size_t)N * D * sizeof(__half);  // 25.6 MB each

  if (ws_size >= 2 * half_rows) {
    __half* Yh = (__half*)d_ws;
    __half* Xh = (__half*)((char*)d_ws + half_rows);

    int n4 = N * D / 4;
    convert_f16_kernel<<<(n4 + 255) / 256, 256, 0, stream>>>(x_in, Xh, n4);

    dim3 g1((N + TM - 1) / TM);
    gemm_xw_f16_kernel<<<g1, 256, 0, stream>>>(x_out, W, Yh, N);

    long long total = (long long)E * 16;
    dim3 g2((unsigned)((total + 255) / 256));
    edge_dot_f16_kernel<<<g2, 256, 0, stream>>>(Yh, Xh, eidx, out, E);
  } else {
    long long total = (long long)E * 64;
    dim3 g((unsigned)((total + 255) / 256));
    edge_bilinear_direct_kernel<<<g, 256, 0, stream>>>(x_out, x_in, W, eidx, out, E);
  }
}

// Round 3
// 259.329 us; speedup vs baseline: 1.4348x; 1.0972x over previous
//
#include <hip/hip_runtime.h>
#include <hip/hip_fp16.h>
#include <math.h>

#define D 128

typedef _Float16 f16x8 __attribute__((ext_vector_type(8)));
typedef float    f32x4 __attribute__((ext_vector_type(4)));
typedef _Float16 h2_t  __attribute__((ext_vector_type(2)));

__device__ __forceinline__ float dot2acc(unsigned ua, unsigned ub, float c) {
#if __has_builtin(__builtin_amdgcn_fdot2)
  return __builtin_amdgcn_fdot2(__builtin_bit_cast(h2_t, ua),
                                __builtin_bit_cast(h2_t, ub), c, false);
#else
  __half2 a = __builtin_bit_cast(__half2, ua);
  __half2 b = __builtin_bit_cast(__half2, ub);
  float2 fa = __half22float2(a), fb = __half22float2(b);
  return fmaf(fa.x, fb.x, fmaf(fa.y, fb.y, c));
#endif
}

__device__ __forceinline__ unsigned pack2(float x, float y) {
  __half2 h;
  h.x = __float2half_rn(x);
  h.y = __float2half_rn(y);
  return __builtin_bit_cast(unsigned, h);
}

// ---------------- Kernel 0: x_in (fp32) -> fp16 ----------------
__global__ __launch_bounds__(256) void convert_f16_kernel(
    const float* __restrict__ x, __half* __restrict__ xh, int n4)
{
  int i = blockIdx.x * 256 + threadIdx.x;
  if (i >= n4) return;
  float4 v = ((const float4*)x)[i];
  uint2 u;
  u.x = pack2(v.x, v.y);
  u.y = pack2(v.z, v.w);
  ((uint2*)xh)[i] = u;
}

// ---------------- Kernel 0b: Wt[n][k] = (half)W[k][n] ----------------
// Coalesced dword reads of W; scattered 2B writes (tiny: 64 KB total, one-off).
__global__ __launch_bounds__(256) void transpose_w_kernel(
    const float* __restrict__ W, __half* __restrict__ Wt)
{
  int o = blockIdx.x * 256 + threadIdx.x;   // 0..16383
  if (o >= D * D) return;
  int k = o >> 7;
  int n = o & 127;
  Wt[n * D + k] = __float2half_rn(W[o]);
}

// ---------------- Kernel 1: Y = X @ W via MFMA fp16 (fp32 accumulate) --------
// 256 threads (4 waves), tile 128 rows x 128 cols x K=128 (single shot).
// LDS: sA/sB 128x128 fp16, granule-rotation swizzle: 16B granule g of row r
// stored at granule (g+r)&15 -> 2-way max bank aliasing on all accesses (free).
__global__ __launch_bounds__(256) void gemm_mfma_kernel(
    const float* __restrict__ X, const __half* __restrict__ Wt,
    __half* __restrict__ Y, int N)
{
  __shared__ __align__(16) __half sA[128 * 128];  // x_out tile (rows swizzled)
  __shared__ __align__(16) __half sB[128 * 128];  // Wt rows (n-major, swizzled)

  const int tid  = threadIdx.x;
  const int row0 = blockIdx.x * 128;

  // Stage A: fp32 global (coalesced float4) -> fp16 swizzled LDS (uint2 writes)
  #pragma unroll
  for (int i = 0; i < 16; i++) {
    int idx = tid + i * 256;       // 0..4095 float4-tasks
    int q   = idx & 31;            // float4 index within row (32 per row)
    int r   = idx >> 5;            // row 0..127
    int gr  = row0 + r;
    float4 v = make_float4(0.f, 0.f, 0.f, 0.f);
    if (gr < N) v = *(const float4*)(X + (size_t)gr * D + q * 4);
    uint2 u;
    u.x = pack2(v.x, v.y);
    u.y = pack2(v.z, v.w);
    int g   = q >> 1;              // 16B granule index (8 halves)
    int sub = q & 1;               // which half of the granule
    int off = r * 128 + (((g + r) & 15) << 3) + (sub << 2);  // in halves
    *(uint2*)(sA + off) = u;
  }
  // Stage B: Wt fp16 (coalesced uint4) -> swizzled LDS (uint4 writes)
  #pragma unroll
  for (int i = 0; i < 8; i++) {
    int idx = tid + i * 256;       // 0..2047 granules
    int g   = idx & 15;
    int n   = idx >> 4;
    uint4 v = *(const uint4*)(Wt + n * 128 + g * 8);
    int off = n * 128 + (((g + n) & 15) << 3);
    *(uint4*)(sB + off) = v;
  }
  __syncthreads();

  const int wave = tid >> 6;
  const int lane = tid & 63;
  const int m    = lane & 15;
  const int quad = lane >> 4;

  f32x4 acc[2][8];
  #pragma unroll
  for (int rt = 0; rt < 2; rt++)
    #pragma unroll
    for (int ct = 0; ct < 8; ct++)
      acc[rt][ct] = (f32x4){0.f, 0.f, 0.f, 0.f};

  #pragma unroll
  for (int ks = 0; ks < 4; ks++) {
    const int g = ks * 4 + quad;   // k-granule for this lane's fragment
    f16x8 bfrag[8];
    #pragma unroll
    for (int ct = 0; ct < 8; ct++) {
      int n = ct * 16 + m;
      bfrag[ct] = *(const f16x8*)(sB + n * 128 + (((g + n) & 15) << 3));
    }
    #pragma unroll
    for (int rt = 0; rt < 2; rt++) {
      int r = wave * 32 + rt * 16 + m;
      f16x8 afrag = *(const f16x8*)(sA + r * 128 + (((g + r) & 15) << 3));
      #pragma unroll
      for (int ct = 0; ct < 8; ct++)
        acc[rt][ct] = __builtin_amdgcn_mfma_f32_16x16x32_f16(
            afrag, bfrag[ct], acc[rt][ct], 0, 0, 0);
    }
  }

  // Epilogue: C/D layout col = lane&15, row = quad*4 + reg  [m89]
  #pragma unroll
  for (int rt = 0; rt < 2; rt++) {
    #pragma unroll
    for (int reg = 0; reg < 4; reg++) {
      int gr = row0 + wave * 32 + rt * 16 + quad * 4 + reg;
      if (gr < N) {
        __half* yrow = Y + (size_t)gr * D;
        #pragma unroll
        for (int ct = 0; ct < 8; ct++)
          yrow[ct * 16 + m] = __float2half_rn(acc[rt][ct][reg]);
      }
    }
  }
}

// ---------------- Kernel 2: out[e] = sigmoid(Yh[src] . Xh[dst]), 2 edges/thread --
__global__ __launch_bounds__(256) void edge_dot2_kernel(
    const __half* __restrict__ Yh, const __half* __restrict__ Xh,
    const int* __restrict__ idx, float* __restrict__ out, int E)
{
  long long gid = (long long)blockIdx.x * 256 + threadIdx.x;
  int slot = (int)(gid >> 4);
  int l    = (int)(gid & 15);
  int e0 = slot * 2;
  if (e0 >= E) return;
  int e1 = e0 + 1;
  bool has1 = (e1 < E);

  int s0 = idx[e0];
  int d0 = idx[E + e0];
  int s1 = has1 ? idx[e1] : s0;
  int d1 = has1 ? idx[E + e1] : d0;

  // 4 independent gather chains in flight
  uint4 a0 = ((const uint4*)(Yh + (size_t)s0 * D))[l];
  uint4 b0 = ((const uint4*)(Xh + (size_t)d0 * D))[l];
  uint4 a1 = ((const uint4*)(Yh + (size_t)s1 * D))[l];
  uint4 b1 = ((const uint4*)(Xh + (size_t)d1 * D))[l];

  float p = 0.f, q = 0.f;
  p = dot2acc(a0.x, b0.x, p);  q = dot2acc(a1.x, b1.x, q);
  p = dot2acc(a0.y, b0.y, p);  q = dot2acc(a1.y, b1.y, q);
  p = dot2acc(a0.z, b0.z, p);  q = dot2acc(a1.z, b1.z, q);
  p = dot2acc(a0.w, b0.w, p);  q = dot2acc(a1.w, b1.w, q);

  p += __shfl_xor(p, 8);  q += __shfl_xor(q, 8);
  p += __shfl_xor(p, 4);  q += __shfl_xor(q, 4);
  p += __shfl_xor(p, 2);  q += __shfl_xor(q, 2);
  p += __shfl_xor(p, 1);  q += __shfl_xor(q, 1);

  if (l == 0) {
    float2 o;
    o.x = 1.0f / (1.0f + __expf(-p));
    o.y = 1.0f / (1.0f + __expf(-q));
    if (has1) *(float2*)(out + e0) = o;   // e0 even -> 8B aligned
    else      out[e0] = o.x;
  }
}

// ---------------- Fallback: direct bilinear per edge (only if ws too small) ----
__global__ __launch_bounds__(256) void edge_bilinear_direct_kernel(
    const float* __restrict__ Xout, const float* __restrict__ Xin,
    const float* __restrict__ W, const int* __restrict__ idx,
    float* __restrict__ out, int E)
{
  long long gid = (long long)blockIdx.x * 256 + threadIdx.x;
  int e = (int)(gid >> 6);
  if (e >= E) return;
  int l = (int)(gid & 63);

  int src = idx[e];
  int dst = idx[E + e];
  const float* a = Xout + (size_t)src * D;
  const float* b = Xin  + (size_t)dst * D;

  float s = 0.f;
  #pragma unroll
  for (int kk = 0; kk < 2; kk++) {
    int k = l + kk * 64;
    float ak = a[k];
    float t = 0.f;
    #pragma unroll 8
    for (int j = 0; j < D; j++) t = fmaf(W[(size_t)k * D + j], b[j], t);
    s = fmaf(ak, t, s);
  }
  #pragma unroll
  for (int off = 32; off >= 1; off >>= 1) s += __shfl_xor(s, off);
  if (l == 0) out[e] = 1.0f / (1.0f + __expf(-s));
}

extern "C" void kernel_launch(void* const* d_in, const int* in_sizes, int n_in,
                              void* d_out, int out_size, void* d_ws, size_t ws_size,
                              hipStream_t stream) {
  const float* x_in  = (const float*)d_in[0];   // [N, 128]
  const float* x_out = (const float*)d_in[1];   // [N, 128]
  const int*   eidx  = (const int*)d_in[2];     // [2, E]
  const float* W     = (const float*)d_in[3];   // [128,128]
  float* out = (float*)d_out;

  const int N = in_sizes[0] / D;
  const int E = in_sizes[2] / 2;

  const size_t half_rows = (size_t)N * D * sizeof(__half);  // 25.6 MB each

  if (ws_size >= 2 * half_rows) {
    __half* Yh = (__half*)d_ws;
    __half* Xh = (__half*)((char*)d_ws + half_rows);
    // 32 KB fp16 W-transpose scratch: use ws tail if it fits, else the head of
    // d_out (safe: edge kernel fully overwrites d_out afterward, same stream).
    __half* Wt;
    if (ws_size >= 2 * half_rows + (size_t)D * D * sizeof(__half))
      Wt = (__half*)((char*)d_ws + 2 * half_rows);
    else
      Wt = (__half*)d_out;

    int n4 = N * D / 4;
    convert_f16_kernel<<<(n4 + 255) / 256, 256, 0, stream>>>(x_in, Xh, n4);

    transpose_w_kernel<<<(D * D + 255) / 256, 256, 0, stream>>>(W, Wt);

    dim3 g1((N + 127) / 128);
    gemm_mfma_kernel<<<g1, 256, 0, stream>>>(x_out, Wt, Yh, N);

    long long slots = (E + 1) / 2;
    long long total = slots * 16;
    dim3 g2((unsigned)((total + 255) / 256));
    edge_dot2_kernel<<<g2, 256, 0, stream>>>(Yh, Xh, eidx, out, E);
  } else {
    long long total = (long long)E * 64;
    dim3 g((unsigned)((total + 255) / 256));
    edge_bilinear_direct_kernel<<<g, 256, 0, stream>>>(x_out, x_in, W, eidx, out, E);
  }
}

// Round 4
// 252.865 us; speedup vs baseline: 1.4715x; 1.0256x over previous
//
#include <hip/hip_runtime.h>
#include <hip/hip_fp16.h>
#include <math.h>

#define D 128
#define CONV_BLOCKS 1024

typedef _Float16 f16x8 __attribute__((ext_vector_type(8)));
typedef float    f32x4 __attribute__((ext_vector_type(4)));
typedef _Float16 h2_t  __attribute__((ext_vector_type(2)));

__device__ __forceinline__ float dot2acc(unsigned ua, unsigned ub, float c) {
#if __has_builtin(__builtin_amdgcn_fdot2)
  return __builtin_amdgcn_fdot2(__builtin_bit_cast(h2_t, ua),
                                __builtin_bit_cast(h2_t, ub), c, false);
#else
  __half2 a = __builtin_bit_cast(__half2, ua);
  __half2 b = __builtin_bit_cast(__half2, ub);
  float2 fa = __half22float2(a), fb = __half22float2(b);
  return fmaf(fa.x, fb.x, fmaf(fa.y, fb.y, c));
#endif
}

__device__ __forceinline__ unsigned pack2(float x, float y) {
  __half2 h;
  h.x = __float2half_rn(x);
  h.y = __float2half_rn(y);
  return __builtin_bit_cast(unsigned, h);
}

// ---------------- Fused prep kernel ----------------
// blocks [0, gemm_blocks): one 128-row MFMA tile of Y = Xout @ W (fp16 out).
//   - A staged fp32->fp16 into swizzled LDS (granule-rotation (g+r)&15: 2-way max).
//   - W transposed in-kernel during B staging (fp32 k-major -> fp16 n-major LDS).
//   - Epilogue: acc -> LDS (reuse sA) -> coalesced uint4 global stores.
// blocks [gemm_blocks, gemm_blocks+CONV_BLOCKS): grid-stride x_in fp32->fp16.
__global__ __launch_bounds__(256) void prep_kernel(
    const float* __restrict__ Xout, const float* __restrict__ Xin,
    const float* __restrict__ W, __half* __restrict__ Yh,
    __half* __restrict__ Xh, int N, int gemm_blocks)
{
  __shared__ __align__(16) __half sA[128 * 128];  // 32 KB (reused as sC in epilogue)
  __shared__ __align__(16) __half sB[128 * 128];  // 32 KB

  const int tid = threadIdx.x;

  if ((int)blockIdx.x >= gemm_blocks) {
    // ---- convert role: Xh = (half)Xin, 4 float4s per thread per step ----
    const int cb = blockIdx.x - gemm_blocks;
    const int n4 = N * (D / 4);
    const int stride = CONV_BLOCKS * 256 * 4;
    for (int base = (cb * 256 + tid) * 4; base < n4; base += stride) {
      float4 v[4];
      #pragma unroll
      for (int j = 0; j < 4; j++)
        if (base + j < n4) v[j] = ((const float4*)Xin)[base + j];
      #pragma unroll
      for (int j = 0; j < 4; j++)
        if (base + j < n4) {
          uint2 u;
          u.x = pack2(v[j].x, v[j].y);
          u.y = pack2(v[j].z, v[j].w);
          ((uint2*)Xh)[base + j] = u;
        }
    }
    return;
  }

  // ---- GEMM role ----
  const int row0 = blockIdx.x * 128;

  // Stage A: fp32 global (coalesced float4) -> fp16 swizzled LDS
  #pragma unroll
  for (int i = 0; i < 16; i++) {
    int idx = tid + i * 256;       // 0..4095 float4-tasks
    int q   = idx & 31;            // float4 index within row
    int r   = idx >> 5;            // row 0..127
    int gr  = row0 + r;
    float4 v = make_float4(0.f, 0.f, 0.f, 0.f);
    if (gr < N) v = *(const float4*)(Xout + (size_t)gr * D + q * 4);
    uint2 u;
    u.x = pack2(v.x, v.y);
    u.y = pack2(v.z, v.w);
    int g   = q >> 1;
    int sub = q & 1;
    int off = r * 128 + (((g + r) & 15) << 3) + (sub << 2);
    *(uint2*)(sA + off) = u;
  }
  // Stage B: transpose W (fp32 k-major) -> fp16 n-major swizzled LDS.
  // sB[n][k-granule (gk+n)&15, j=k&7] = (half)W[k][n]; coalesced dword reads.
  #pragma unroll
  for (int i = 0; i < 64; i++) {
    int o = tid + i * 256;         // 0..16383
    int k = o >> 7;
    int n = o & 127;
    __half h = __float2half_rn(W[o]);
    int gk = k >> 3;
    sB[n * 128 + (((gk + n) & 15) << 3) + (k & 7)] = h;
  }
  __syncthreads();

  const int wave = tid >> 6;
  const int lane = tid & 63;
  const int m    = lane & 15;
  const int quad = lane >> 4;

  f32x4 acc[2][8];
  #pragma unroll
  for (int rt = 0; rt < 2; rt++)
    #pragma unroll
    for (int ct = 0; ct < 8; ct++)
      acc[rt][ct] = (f32x4){0.f, 0.f, 0.f, 0.f};

  #pragma unroll
  for (int ks = 0; ks < 4; ks++) {
    const int g = ks * 4 + quad;
    f16x8 bfrag[8];
    #pragma unroll
    for (int ct = 0; ct < 8; ct++) {
      int n = ct * 16 + m;
      bfrag[ct] = *(const f16x8*)(sB + n * 128 + (((g + n) & 15) << 3));
    }
    #pragma unroll
    for (int rt = 0; rt < 2; rt++) {
      int r = wave * 32 + rt * 16 + m;
      f16x8 afrag = *(const f16x8*)(sA + r * 128 + (((g + r) & 15) << 3));
      #pragma unroll
      for (int ct = 0; ct < 8; ct++)
        acc[rt][ct] = __builtin_amdgcn_mfma_f32_16x16x32_f16(
            afrag, bfrag[ct], acc[rt][ct], 0, 0, 0);
    }
  }

  // Epilogue: acc -> sC (row-major fp16, reuse sA) -> coalesced uint4 stores.
  __syncthreads();
  __half* sC = sA;
  #pragma unroll
  for (int rt = 0; rt < 2; rt++)
    #pragma unroll
    for (int reg = 0; reg < 4; reg++) {
      int r = wave * 32 + rt * 16 + quad * 4 + reg;
      #pragma unroll
      for (int ct = 0; ct < 8; ct++)
        sC[r * 128 + ct * 16 + m] = __float2half_rn(acc[rt][ct][reg]);
    }
  __syncthreads();
  #pragma unroll
  for (int i = 0; i < 8; i++) {
    int idx = tid + i * 256;       // 0..2047 granules
    int r   = idx >> 4;
    int gq  = idx & 15;
    int gr  = row0 + r;
    if (gr < N)
      *(uint4*)(Yh + (size_t)gr * D + gq * 8) = *(const uint4*)(sC + r * 128 + gq * 8);
  }
}

// ---------------- Edge kernel: out[e] = sigmoid(Yh[src] . Xh[dst]), 2 edges/thread --
__global__ __launch_bounds__(256) void edge_dot2_kernel(
    const __half* __restrict__ Yh, const __half* __restrict__ Xh,
    const int* __restrict__ idx, float* __restrict__ out, int E)
{
  long long gid = (long long)blockIdx.x * 256 + threadIdx.x;
  int slot = (int)(gid >> 4);
  int l    = (int)(gid & 15);
  int e0 = slot * 2;
  if (e0 >= E) return;
  int e1 = e0 + 1;
  bool has1 = (e1 < E);

  int s0 = idx[e0];
  int d0 = idx[E + e0];
  int s1 = has1 ? idx[e1] : s0;
  int d1 = has1 ? idx[E + e1] : d0;

  uint4 a0 = ((const uint4*)(Yh + (size_t)s0 * D))[l];
  uint4 b0 = ((const uint4*)(Xh + (size_t)d0 * D))[l];
  uint4 a1 = ((const uint4*)(Yh + (size_t)s1 * D))[l];
  uint4 b1 = ((const uint4*)(Xh + (size_t)d1 * D))[l];

  float p = 0.f, q = 0.f;
  p = dot2acc(a0.x, b0.x, p);  q = dot2acc(a1.x, b1.x, q);
  p = dot2acc(a0.y, b0.y, p);  q = dot2acc(a1.y, b1.y, q);
  p = dot2acc(a0.z, b0.z, p);  q = dot2acc(a1.z, b1.z, q);
  p = dot2acc(a0.w, b0.w, p);  q = dot2acc(a1.w, b1.w, q);

  p += __shfl_xor(p, 8);  q += __shfl_xor(q, 8);
  p += __shfl_xor(p, 4);  q += __shfl_xor(q, 4);
  p += __shfl_xor(p, 2);  q += __shfl_xor(q, 2);
  p += __shfl_xor(p, 1);  q += __shfl_xor(q, 1);

  if (l == 0) {
    float2 o;
    o.x = 1.0f / (1.0f + __expf(-p));
    o.y = 1.0f / (1.0f + __expf(-q));
    if (has1) *(float2*)(out + e0) = o;
    else      out[e0] = o.x;
  }
}

// ---------------- Fallback: direct bilinear per edge (only if ws too small) ----
__global__ __launch_bounds__(256) void edge_bilinear_direct_kernel(
    const float* __restrict__ Xout, const float* __restrict__ Xin,
    const float* __restrict__ W, const int* __restrict__ idx,
    float* __restrict__ out, int E)
{
  long long gid = (long long)blockIdx.x * 256 + threadIdx.x;
  int e = (int)(gid >> 6);
  if (e >= E) return;
  int l = (int)(gid & 63);

  int src = idx[e];
  int dst = idx[E + e];
  const float* a = Xout + (size_t)src * D;
  const float* b = Xin  + (size_t)dst * D;

  float s = 0.f;
  #pragma unroll
  for (int kk = 0; kk < 2; kk++) {
    int k = l + kk * 64;
    float ak = a[k];
    float t = 0.f;
    #pragma unroll 8
    for (int j = 0; j < D; j++) t = fmaf(W[(size_t)k * D + j], b[j], t);
    s = fmaf(ak, t, s);
  }
  #pragma unroll
  for (int off = 32; off >= 1; off >>= 1) s += __shfl_xor(s, off);
  if (l == 0) out[e] = 1.0f / (1.0f + __expf(-s));
}

extern "C" void kernel_launch(void* const* d_in, const int* in_sizes, int n_in,
                              void* d_out, int out_size, void* d_ws, size_t ws_size,
                              hipStream_t stream) {
  const float* x_in  = (const float*)d_in[0];   // [N, 128]
  const float* x_out = (const float*)d_in[1];   // [N, 128]
  const int*   eidx  = (const int*)d_in[2];     // [2, E]
  const float* W     = (const float*)d_in[3];   // [128,128]
  float* out = (float*)d_out;

  const int N = in_sizes[0] / D;
  const int E = in_sizes[2] / 2;

  const size_t half_rows = (size_t)N * D * sizeof(__half);  // 25.6 MB each

  if (ws_size >= 2 * half_rows) {
    __half* Yh = (__half*)d_ws;
    __half* Xh = (__half*)((char*)d_ws + half_rows);

    int gemm_blocks = (N + 127) / 128;
    dim3 g1(gemm_blocks + CONV_BLOCKS);
    prep_kernel<<<g1, 256, 0, stream>>>(x_out, x_in, W, Yh, Xh, N, gemm_blocks);

    long long slots = (E + 1) / 2;
    long long total = slots * 16;
    dim3 g2((unsigned)((total + 255) / 256));
    edge_dot2_kernel<<<g2, 256, 0, stream>>>(Yh, Xh, eidx, out, E);
  } else {
    long long total = (long long)E * 64;
    dim3 g((unsigned)((total + 255) / 256));
    edge_bilinear_direct_kernel<<<g, 256, 0, stream>>>(x_out, x_in, W, eidx, out, E);
  }
}